// Round 21
// baseline (231.715 us; speedup 1.0000x reference)
//
#include <hip/hip_runtime.h>
#include <hip/hip_bf16.h>

// ---------------- constants ----------------
#define C_IN  128
#define C_HID 256
#define C_OUT 128

#define BIN_SHIFT 10
#define BIN_SIZE  1024
#define NBINS_MAX 128
#define CAP       32768          // per-bin capacity (16 slots x 2048)
#define NSLOT     16
#define SUBCAP    (CAP / NSLOT)  // 2048 per (bin,slot) sub-region
#define CHUNK_A   8192           // edges per bin-append block

typedef __attribute__((ext_vector_type(8))) short short8;
typedef __attribute__((ext_vector_type(4))) float f32x4;

static __device__ __forceinline__ unsigned short f2bf(float f) {
    __hip_bfloat16 h = __float2bfloat16(f);
    return __builtin_bit_cast(unsigned short, h);
}
static __device__ __forceinline__ float bf2f(unsigned short u) {
    unsigned int x = ((unsigned int)u) << 16;
    return __builtin_bit_cast(float, x);
}

// ---------------- fused prep: quant x->int8/row-scale | pack W1 | pack W2 | bin-append ----------------
static __device__ __forceinline__ void pack_one(const float* __restrict__ W,
                                                unsigned short* __restrict__ Wp,
                                                int o, int NKS, int M) {
    int j    = o & 7;
    int lane = (o >> 3) & 63;
    int rest = o >> 9;
    int ks = rest % NKS;
    int ct = rest / NKS;
    int k = ks * 32 + (lane >> 4) * 8 + j;
    int m = ct * 16 + (lane & 15);
    Wp[o] = f2bf(W[(size_t)k * M + m]);
}

#define CVT_BLOCKS   512
#define PACK_BLOCKS  128     // 32768 / 256

__global__ __launch_bounds__(256) void prep_kernel(const float* __restrict__ x,
                                                   unsigned char* __restrict__ xq,
                                                   float* __restrict__ xscale,
                                                   const float* __restrict__ W1,
                                                   unsigned short* __restrict__ w1p,
                                                   const float* __restrict__ W2,
                                                   unsigned short* __restrict__ w2p,
                                                   const int* __restrict__ src,
                                                   const int* __restrict__ dst,
                                                   unsigned int* __restrict__ binned,
                                                   int* __restrict__ gbin_cnt,
                                                   int e, int n) {
    __shared__ int lh[NBINS_MAX];    // sweep-1 local histogram
    __shared__ int lgb[NBINS_MAX];   // sub-region base per bin for this block
    __shared__ int lh2[NBINS_MAX];   // sweep-2 rank counters
    const int b = blockIdx.x, tid = threadIdx.x;
    if (b < CVT_BLOCKS) {
        // int8 row quantization: 32 lanes per row, 8 rows per block, grid-stride
        const int slane = tid & 31;
        const int subrow = tid >> 5;
        for (int row = b * 8 + subrow; row < n; row += CVT_BLOCKS * 8) {
            float4 v = *(const float4*)&x[(size_t)row * C_IN + slane * 4];
            float m = fmaxf(fmaxf(fabsf(v.x), fabsf(v.y)), fmaxf(fabsf(v.z), fabsf(v.w)));
            #pragma unroll
            for (int off = 16; off; off >>= 1) m = fmaxf(m, __shfl_xor(m, off));
            float inv = (m > 0.f) ? 127.f / m : 0.f;
            int q0 = (int)rintf(v.x * inv), q1 = (int)rintf(v.y * inv);
            int q2 = (int)rintf(v.z * inv), q3 = (int)rintf(v.w * inv);
            unsigned int p = ((unsigned)q0 & 0xff) | (((unsigned)q1 & 0xff) << 8) |
                             (((unsigned)q2 & 0xff) << 16) | (((unsigned)q3 & 0xff) << 24);
            *(unsigned int*)&xq[(size_t)row * C_IN + slane * 4] = p;
            if (slane == 0) xscale[row] = m * (1.f / 127.f);
        }
    } else if (b < CVT_BLOCKS + PACK_BLOCKS) {
        pack_one(W1, w1p, (b - CVT_BLOCKS) * 256 + tid, C_IN / 32, C_HID);
    } else if (b < CVT_BLOCKS + 2 * PACK_BLOCKS) {
        pack_one(W2, w2p, (b - CVT_BLOCKS - PACK_BLOCKS) * 256 + tid, C_HID / 32, C_OUT);
    } else {
        const int cb = b - CVT_BLOCKS - 2 * PACK_BLOCKS;
        const int slot = cb & (NSLOT - 1);           // stripe global counters 16-way
        const int start = cb * CHUNK_A;
        const int end = min(start + CHUNK_A, e);
        const int nbins = (n + BIN_SIZE - 1) >> BIN_SHIFT;
        for (int j = tid; j < nbins; j += 256) { lh[j] = 0; lh2[j] = 0; }
        __syncthreads();
        for (int i = start + tid; i < end; i += 256) {
            unsigned d = (unsigned)dst[i], s = (unsigned)src[i];
            if (d < (unsigned)n && s < (unsigned)n)
                atomicAdd(&lh[d >> BIN_SHIFT], 1);
        }
        __syncthreads();
        for (int j = tid; j < nbins; j += 256) {
            int c = lh[j];
            lgb[j] = c ? atomicAdd(&gbin_cnt[slot * NBINS_MAX + j], c) : 0;
        }
        __syncthreads();
        for (int i = start + tid; i < end; i += 256) {
            unsigned d = (unsigned)dst[i], s = (unsigned)src[i];
            if (d < (unsigned)n && s < (unsigned)n) {
                int bin = d >> BIN_SHIFT;
                int r = atomicAdd(&lh2[bin], 1);
                int pos = lgb[bin] + r;
                if (pos < SUBCAP)
                    binned[(size_t)bin * CAP + slot * SUBCAP + pos] =
                        (s << BIN_SHIFT) | (d & (BIN_SIZE - 1));
            }
        }
    }
}

// ---------------- bin scan: totals over 16 slots -> exclusive scan -> bin_base; row_start[n]=total
__global__ __launch_bounds__(1024) void binscan_kernel(const int* __restrict__ gbin_cnt,
                                                       int* __restrict__ bin_base,
                                                       int* __restrict__ row_start,
                                                       int nbins, int n) {
    const int tid = threadIdx.x, lane = tid & 63, w = tid >> 6;
    int v = 0;
    if (tid < nbins) {
        #pragma unroll
        for (int s = 0; s < NSLOT; ++s) {
            int c = gbin_cnt[s * NBINS_MAX + tid];
            v += (c < SUBCAP) ? c : SUBCAP;          // clamp overflowed sub-regions
        }
    }
    int x = v;
    #pragma unroll
    for (int off = 1; off < 64; off <<= 1) {
        int y = __shfl_up(x, off);
        if (lane >= off) x += y;
    }
    __shared__ int ws[16];
    if (lane == 63) ws[w] = x;
    __syncthreads();
    int woff = 0, total = 0;
    #pragma unroll
    for (int j = 0; j < 16; ++j) {
        int s = ws[j];
        if (j < w) woff += s;
        total += s;
    }
    if (tid < nbins) bin_base[tid] = woff + (x - v);
    if (tid == 0) { bin_base[nbins] = total; row_start[n] = total; }
}

// ---------------- per-bin CSR build: block b owns nodes [b*1024, b*1024+1024)
// walks the 16 slot sub-regions of its bin; also writes dinv and dscale = dinv*xscale
__global__ __launch_bounds__(1024) void bincsr_kernel(const unsigned int* __restrict__ binned,
                                                      const int* __restrict__ bin_base,
                                                      const int* __restrict__ gbin_cnt,
                                                      const float* __restrict__ xscale,
                                                      int* __restrict__ csr_src,
                                                      int* __restrict__ row_start,
                                                      float* __restrict__ dinv,
                                                      float* __restrict__ dscale, int n) {
    __shared__ int h[BIN_SIZE];
    __shared__ int ex[BIN_SIZE];
    __shared__ int ws[16];
    __shared__ int scnt[NSLOT];
    const int b = blockIdx.x, tid = threadIdx.x, lane = tid & 63, w = tid >> 6;
    h[tid] = 0;
    if (tid < NSLOT) {
        int c = gbin_cnt[tid * NBINS_MAX + b];
        scnt[tid] = (c < SUBCAP) ? c : SUBCAP;
    }
    __syncthreads();
    const int base = bin_base[b];
    const size_t boff = (size_t)b * CAP;
    #pragma unroll
    for (int s = 0; s < NSLOT; ++s) {
        const int cs = scnt[s];
        for (int i = tid; i < cs; i += BIN_SIZE)
            atomicAdd(&h[binned[boff + s * SUBCAP + i] & (BIN_SIZE - 1)], 1);
    }
    __syncthreads();
    const int v = h[tid];
    int x = v;
    #pragma unroll
    for (int off = 1; off < 64; off <<= 1) {
        int y = __shfl_up(x, off);
        if (lane >= off) x += y;
    }
    if (lane == 63) ws[w] = x;
    __syncthreads();
    int woff = 0;
    #pragma unroll
    for (int j = 0; j < 16; ++j)
        if (j < w) woff += ws[j];
    const int excl = woff + (x - v);
    ex[tid] = excl;
    const int node = b * BIN_SIZE + tid;
    if (node < n) {
        row_start[node] = base + excl;
        float di = rsqrtf((float)(v + 1));           // +1 self loop
        dinv[node] = di;
        dscale[node] = di * xscale[node];
    }
    __syncthreads();
    h[tid] = 0;                                      // reuse as rank counters
    __syncthreads();
    #pragma unroll
    for (int s = 0; s < NSLOT; ++s) {
        const int cs = scnt[s];
        for (int i = tid; i < cs; i += BIN_SIZE) {
            unsigned p = binned[boff + s * SUBCAP + i];
            int dl = p & (BIN_SIZE - 1);
            int r = atomicAdd(&h[dl], 1);
            csr_src[base + ex[dl] + r] = (int)(p >> BIN_SHIFT);
        }
    }
}

// ---------------- MFMA GEMM: C[n,M] = A[n,K] bf16 @ W[K,M] (packed bf16) ----------------
// Epilogue: optional relu(v+bias); output bf16, or int8 + per-row scale (dscale_out = dinv*max/127)
template<int K, int M, bool BIASRELU, bool OUTINT8>
__global__ __launch_bounds__(256) void gemm_mfma_kernel(const unsigned short* __restrict__ A,
                                                        const unsigned short* __restrict__ Wp,
                                                        void* __restrict__ C_v,
                                                        const float* __restrict__ bias,
                                                        const float* __restrict__ dinv,
                                                        float* __restrict__ dscale_out, int n) {
    constexpr int NKS = K / 32;
    constexpr int NCT = M / 16;
    __shared__ unsigned short wl[K * M];            // 64 KB
    const int tid  = threadIdx.x;
    const int lane = tid & 63;
    const int wid  = tid >> 6;

    for (int i = tid; i < K * M / 8; i += 256)
        *(uint4*)&wl[(size_t)i * 8] = *(const uint4*)&Wp[(size_t)i * 8];
    __syncthreads();

    const int ntiles = (n + 63) / 64;
    for (int t = blockIdx.x; t < ntiles; t += gridDim.x) {
        const int row0 = t * 64 + wid * 16;
        int arow = row0 + (lane & 15);
        if (arow > n - 1) arow = n - 1;             // clamp (garbage rows masked at store)
        const unsigned short* ap = A + (size_t)arow * K + (lane >> 4) * 8;

        short8 afrag[NKS];
        #pragma unroll
        for (int ks = 0; ks < NKS; ++ks)
            afrag[ks] = *(const short8*)(ap + ks * 32);

        f32x4 acc[NCT] = {};
        #pragma unroll
        for (int ks = 0; ks < NKS; ++ks) {
            #pragma unroll
            for (int ct = 0; ct < NCT; ++ct) {
                short8 b = *(const short8*)&wl[((ct * NKS + ks) * 64 + lane) * 8];
                acc[ct] = __builtin_amdgcn_mfma_f32_16x16x32_bf16(afrag[ks], b, acc[ct], 0, 0, 0);
            }
        }

        // C/D layout: col = lane&15, row = (lane>>4)*4 + r   [verified m89]
        const int crow0 = row0 + (lane >> 4) * 4;
        const int ccol  = lane & 15;
        if (OUTINT8) {
            #pragma unroll
            for (int r = 0; r < 4; ++r) {
                float m = 0.f;
                #pragma unroll
                for (int ct = 0; ct < NCT; ++ct) m = fmaxf(m, fabsf(acc[ct][r]));
                #pragma unroll
                for (int off = 1; off < 16; off <<= 1) m = fmaxf(m, __shfl_xor(m, off));
                float inv = (m > 0.f) ? 127.f / m : 0.f;
                int row = crow0 + r;
                if (row < n) {
                    #pragma unroll
                    for (int ct = 0; ct < NCT; ++ct) {
                        int q = (int)rintf(acc[ct][r] * inv);
                        ((signed char*)C_v)[(size_t)row * M + ct * 16 + ccol] = (signed char)q;
                    }
                    if (ccol == 0) dscale_out[row] = dinv[row] * m * (1.f / 127.f);
                }
            }
        } else {
            #pragma unroll
            for (int ct = 0; ct < NCT; ++ct) {
                float bv = BIASRELU ? bias[ct * 16 + ccol] : 0.f;
                #pragma unroll
                for (int r = 0; r < 4; ++r) {
                    int row = crow0 + r;
                    if (row < n) {
                        float v = acc[ct][r];
                        if (BIASRELU) v = fmaxf(v + bv, 0.f);
                        ((unsigned short*)C_v)[(size_t)row * M + ct * 16 + ccol] = f2bf(v);
                    }
                }
            }
        }
    }
}

// ---------------- aggregation: out = [bias +] cw[n]*dn*H[n] + sum cw[s]*dn*H[s]
// cw = dscale (int8 H: dinv*scale) or dinv (bf16 H). dn = dinv[node].
// CH=128: 2 nodes/wave (32 lanes/node, 4 ch/lane). Edge loop unrolled x4 for MLP.
template<int CH, bool INT8IN, bool HASBIAS, bool LN>
__global__ __launch_bounds__(256) void agg_kernel(const void* __restrict__ H_v,
                                                  const int* __restrict__ row_start,
                                                  const int* __restrict__ csr_src,
                                                  const float* __restrict__ dinv,
                                                  const float* __restrict__ cw,
                                                  const float* __restrict__ bias,
                                                  const float* __restrict__ gamma,
                                                  const float* __restrict__ beta,
                                                  void* __restrict__ out_v, int n) {
    constexpr int SUBW = 32;                        // lanes per node
    static_assert(CH == SUBW * 4, "layout");
    const int lane = threadIdx.x & 63;
    const int wid  = threadIdx.x >> 6;
    int node = blockIdx.x * 8 + wid * 2 + (lane >> 5);
    if (node >= n) return;
    const int slane = lane & (SUBW - 1);
    const int c0 = slane * 4;

    const unsigned char*  H8  = (const unsigned char*)H_v;
    const unsigned short* H16 = (const unsigned short*)H_v;

    const float dn = dinv[node];
    const int e0 = row_start[node], e1 = row_start[node + 1];

    float acc[4];
    #define LOAD4(sidx, v0, v1, v2, v3)                                             \
        float v0, v1, v2, v3;                                                       \
        if (INT8IN) {                                                               \
            unsigned int p = *(const unsigned int*)&H8[(size_t)(sidx) * CH + c0];   \
            v0 = (float)(int)(signed char)(p & 0xff);                               \
            v1 = (float)(int)(signed char)((p >> 8) & 0xff);                        \
            v2 = (float)(int)(signed char)((p >> 16) & 0xff);                       \
            v3 = (float)(int)(signed char)(p >> 24);                                \
        } else {                                                                    \
            ushort4 hh = *(const ushort4*)&H16[(size_t)(sidx) * CH + c0];           \
            v0 = bf2f(hh.x); v1 = bf2f(hh.y); v2 = bf2f(hh.z); v3 = bf2f(hh.w);     \
        }
    {   // self loop: coeff = dn * cw[node]
        float c = dn * cw[node];
        LOAD4(node, h0, h1, h2, h3)
        acc[0] = h0 * c; acc[1] = h1 * c; acc[2] = h2 * c; acc[3] = h3 * c;
    }
    int e = e0;
    for (; e + 4 <= e1; e += 4) {
        int s0 = csr_src[e + 0], s1 = csr_src[e + 1];
        int s2 = csr_src[e + 2], s3 = csr_src[e + 3];
        float w0 = cw[s0] * dn, w1 = cw[s1] * dn;
        float w2 = cw[s2] * dn, w3 = cw[s3] * dn;
        LOAD4(s0, a0, a1, a2, a3)
        LOAD4(s1, b0, b1, b2, b3)
        LOAD4(s2, c0v, c1v, c2v, c3v)
        LOAD4(s3, d0, d1, d2, d3)
        acc[0] += a0 * w0;  acc[1] += a1 * w0;  acc[2] += a2 * w0;  acc[3] += a3 * w0;
        acc[0] += b0 * w1;  acc[1] += b1 * w1;  acc[2] += b2 * w1;  acc[3] += b3 * w1;
        acc[0] += c0v * w2; acc[1] += c1v * w2; acc[2] += c2v * w2; acc[3] += c3v * w2;
        acc[0] += d0 * w3;  acc[1] += d1 * w3;  acc[2] += d2 * w3;  acc[3] += d3 * w3;
    }
    for (; e < e1; ++e) {
        int s = csr_src[e];
        float c = cw[s] * dn;
        LOAD4(s, h0, h1, h2, h3)
        acc[0] += h0 * c; acc[1] += h1 * c; acc[2] += h2 * c; acc[3] += h3 * c;
    }
    #undef LOAD4

    if (HASBIAS) {
        float4 bi = *(const float4*)&bias[c0];
        acc[0] += bi.x; acc[1] += bi.y; acc[2] += bi.z; acc[3] += bi.w;
    }

    if (LN) {
        // fused LayerNorm over the sub-wave (32 lanes hold the full row)
        float s = acc[0] + acc[1] + acc[2] + acc[3];
        float ss = acc[0]*acc[0] + acc[1]*acc[1] + acc[2]*acc[2] + acc[3]*acc[3];
        #pragma unroll
        for (int off = SUBW / 2; off; off >>= 1) {
            s  += __shfl_xor(s, off);
            ss += __shfl_xor(ss, off);
        }
        float mu  = s * (1.f / (float)CH);
        float var = ss * (1.f / (float)CH) - mu * mu;
        float rstd = rsqrtf(var + 1e-5f);
        float4 g = *(const float4*)&gamma[c0];
        float4 b = *(const float4*)&beta[c0];
        f32x4 o;
        o[0] = (acc[0] - mu) * rstd * g.x + b.x;
        o[1] = (acc[1] - mu) * rstd * g.y + b.y;
        o[2] = (acc[2] - mu) * rstd * g.z + b.z;
        o[3] = (acc[3] - mu) * rstd * g.w + b.w;
        float* out = (float*)out_v;
        __builtin_nontemporal_store(o, (f32x4*)&out[(size_t)node * CH + c0]);  // final out: write-only
    } else {
        // bf16 output (re-read by next gemm as MFMA A-operand)
        ushort4 o4;
        o4.x = f2bf(acc[0]); o4.y = f2bf(acc[1]);
        o4.z = f2bf(acc[2]); o4.w = f2bf(acc[3]);
        unsigned short* out = (unsigned short*)out_v;
        *(ushort4*)&out[(size_t)node * CH + c0] = o4;
    }
}

extern "C" void kernel_launch(void* const* d_in, const int* in_sizes, int n_in,
                              void* d_out, int out_size, void* d_ws, size_t ws_size,
                              hipStream_t stream) {
    const float* x     = (const float*)d_in[0];
    const int*   ei    = (const int*)d_in[1];     // int32 (harness: integer -> const int*)
    const float* W1    = (const float*)d_in[2];
    const float* b1    = (const float*)d_in[3];
    const float* W2    = (const float*)d_in[4];
    const float* b2    = (const float*)d_in[5];
    const float* gamma = (const float*)d_in[6];
    const float* beta  = (const float*)d_in[7];
    float* out = (float*)d_out;

    const int N = in_sizes[0] / C_IN;
    const int E = in_sizes[1] / 2;
    const int* src = ei;
    const int* dst = ei + E;
    const int NBINS = (N + BIN_SIZE - 1) >> BIN_SHIFT;
    const int NBINA = (E + CHUNK_A - 1) / CHUNK_A;

    // workspace layout
    unsigned char*  xq  = (unsigned char*)d_ws;                     // N*128 B (x int8)
    unsigned short* xa  = (unsigned short*)(xq + (size_t)N * C_IN); // N*128 bf16 (S·x)
    unsigned short* g16 = xa + (size_t)N * C_IN;                    // N*256 bf16
    unsigned char*  h8  = (unsigned char*)(g16 + (size_t)N * C_HID);// N*128 B (g@W2 int8)
    unsigned short* w1p = (unsigned short*)(h8 + (size_t)N * C_OUT);// 128*256
    unsigned short* w2p = w1p + C_IN * C_HID;                       // 256*128
    float* dinv    = (float*)(w2p + C_HID * C_OUT);                 // N
    float* dscale  = dinv + N;                                      // N (dinv*xscale)
    float* xscale  = dscale + N;                                    // N
    float* dscale2 = xscale + N;                                    // N (dinv*hscale)
    int*   row_start = (int*)(dscale2 + N);                         // N+1 (pad 4)
    int*   gbin_cnt  = row_start + N + 4;                           // NSLOT*NBINS_MAX
    int*   bin_base  = gbin_cnt + NSLOT * NBINS_MAX;                // NBINS_MAX+4
    unsigned int* binned = (unsigned int*)(bin_base + NBINS_MAX + 4);  // NBINS_MAX*CAP
    int*   csr_src   = (int*)(binned + (size_t)NBINS_MAX * CAP);       // E

    hipMemsetAsync(gbin_cnt, 0, NSLOT * NBINS_MAX * sizeof(int), stream);

    // fused: quant x->int8 | pack W1 | pack W2 | bin-append edges (slot-striped counters)
    prep_kernel<<<CVT_BLOCKS + 2 * PACK_BLOCKS + NBINA, 256, 0, stream>>>(
        x, xq, xscale, W1, w1p, W2, w2p, src, dst, binned, gbin_cnt, E, N);
    binscan_kernel<<<1, 1024, 0, stream>>>(gbin_cnt, bin_base, row_start, NBINS, N);
    bincsr_kernel<<<NBINS, 1024, 0, stream>>>(binned, bin_base, gbin_cnt, xscale,
                                              csr_src, row_start, dinv, dscale, N);

    // layer 1 (linearity): xa = S·x (int8 gather) ; g = relu(xa@W1 + b1)
    agg_kernel<C_IN, true, false, false><<<(N + 7) / 8, 256, 0, stream>>>(
        (const void*)xq, row_start, csr_src, dinv, dscale,
        nullptr, nullptr, nullptr, (void*)xa, N);
    gemm_mfma_kernel<C_IN, C_HID, true, false><<<512, 256, 0, stream>>>(
        xa, w1p, (void*)g16, b1, nullptr, nullptr, N);

    // layer 2: h8 = g@W2 (int8 + row scale) ; out = LN(S·h8 + b2)
    gemm_mfma_kernel<C_HID, C_OUT, false, true><<<512, 256, 0, stream>>>(
        g16, w2p, (void*)h8, nullptr, dinv, dscale2, N);
    agg_kernel<C_OUT, true, true, true><<<(N + 7) / 8, 256, 0, stream>>>(
        (const void*)h8, row_start, csr_src, dinv, dscale2, b2, gamma, beta, (void*)out, N);
}

// Round 23
// 217.429 us; speedup vs baseline: 1.0657x; 1.0657x over previous
//
#include <hip/hip_runtime.h>
#include <hip/hip_bf16.h>

// ---------------- constants ----------------
#define C_IN  128
#define C_HID 256
#define C_OUT 128

#define BIN_SHIFT 10
#define BIN_SIZE  1024
#define NBINS_MAX 128
#define CAP       32768          // per-bin capacity (16 slots x 2048)
#define NSLOT     16
#define SUBCAP    (CAP / NSLOT)  // 2048 per (bin,slot) sub-region
#define CHUNK_A   4096           // edges per bin-append block

typedef __attribute__((ext_vector_type(8))) short short8;
typedef __attribute__((ext_vector_type(4))) float f32x4;

static __device__ __forceinline__ unsigned short f2bf(float f) {
    __hip_bfloat16 h = __float2bfloat16(f);
    return __builtin_bit_cast(unsigned short, h);
}
static __device__ __forceinline__ float bf2f(unsigned short u) {
    unsigned int x = ((unsigned int)u) << 16;
    return __builtin_bit_cast(float, x);
}

// ---------------- fused prep: quant x->int8/row-scale | pack W1 | pack W2 | bin-append ----------------
static __device__ __forceinline__ void pack_one(const float* __restrict__ W,
                                                unsigned short* __restrict__ Wp,
                                                int o, int NKS, int M) {
    int j    = o & 7;
    int lane = (o >> 3) & 63;
    int rest = o >> 9;
    int ks = rest % NKS;
    int ct = rest / NKS;
    int k = ks * 32 + (lane >> 4) * 8 + j;
    int m = ct * 16 + (lane & 15);
    Wp[o] = f2bf(W[(size_t)k * M + m]);
}

#define CVT_BLOCKS   1024
#define PACK_BLOCKS  128     // 32768 / 256

__global__ __launch_bounds__(256) void prep_kernel(const float* __restrict__ x,
                                                   unsigned char* __restrict__ xq,
                                                   float* __restrict__ xscale,
                                                   const float* __restrict__ W1,
                                                   unsigned short* __restrict__ w1p,
                                                   const float* __restrict__ W2,
                                                   unsigned short* __restrict__ w2p,
                                                   const int* __restrict__ src,
                                                   const int* __restrict__ dst,
                                                   unsigned int* __restrict__ binned,
                                                   int* __restrict__ gbin_cnt,
                                                   int e, int n) {
    __shared__ int lh[NBINS_MAX];    // sweep-1 local histogram
    __shared__ int lgb[NBINS_MAX];   // sub-region base per bin for this block
    __shared__ int lh2[NBINS_MAX];   // sweep-2 rank counters
    const int b = blockIdx.x, tid = threadIdx.x;
    if (b < CVT_BLOCKS) {
        // int8 row quantization: 32 lanes per row, 8 rows per block, grid-stride
        const int slane = tid & 31;
        const int subrow = tid >> 5;
        for (int row = b * 8 + subrow; row < n; row += CVT_BLOCKS * 8) {
            float4 v = *(const float4*)&x[(size_t)row * C_IN + slane * 4];
            float m = fmaxf(fmaxf(fabsf(v.x), fabsf(v.y)), fmaxf(fabsf(v.z), fabsf(v.w)));
            #pragma unroll
            for (int off = 16; off; off >>= 1) m = fmaxf(m, __shfl_xor(m, off));
            float inv = (m > 0.f) ? 127.f / m : 0.f;
            int q0 = (int)rintf(v.x * inv), q1 = (int)rintf(v.y * inv);
            int q2 = (int)rintf(v.z * inv), q3 = (int)rintf(v.w * inv);
            unsigned int p = ((unsigned)q0 & 0xff) | (((unsigned)q1 & 0xff) << 8) |
                             (((unsigned)q2 & 0xff) << 16) | (((unsigned)q3 & 0xff) << 24);
            *(unsigned int*)&xq[(size_t)row * C_IN + slane * 4] = p;
            if (slane == 0) xscale[row] = m * (1.f / 127.f);
        }
    } else if (b < CVT_BLOCKS + PACK_BLOCKS) {
        pack_one(W1, w1p, (b - CVT_BLOCKS) * 256 + tid, C_IN / 32, C_HID);
    } else if (b < CVT_BLOCKS + 2 * PACK_BLOCKS) {
        pack_one(W2, w2p, (b - CVT_BLOCKS - PACK_BLOCKS) * 256 + tid, C_HID / 32, C_OUT);
    } else {
        const int cb = b - CVT_BLOCKS - 2 * PACK_BLOCKS;
        const int slot = cb & (NSLOT - 1);           // stripe global counters 16-way
        const int start = cb * CHUNK_A;
        const int end = min(start + CHUNK_A, e);
        const int nbins = (n + BIN_SIZE - 1) >> BIN_SHIFT;
        for (int j = tid; j < nbins; j += 256) { lh[j] = 0; lh2[j] = 0; }
        __syncthreads();
        // sweep 1: histogram (int4 edge loads: 4 edges/lane/iter)
        const int nvec = (end - start) >> 2;         // int4 groups in this chunk
        const int4* dst4 = (const int4*)(dst + start);
        const int4* src4 = (const int4*)(src + start);
        for (int i = tid; i < nvec; i += 256) {
            int4 d4 = dst4[i];
            int4 s4 = src4[i];
            #define C1(dd, ss) { unsigned d = (unsigned)(dd), s = (unsigned)(ss);   \
                if (d < (unsigned)n && s < (unsigned)n) atomicAdd(&lh[d >> BIN_SHIFT], 1); }
            C1(d4.x, s4.x) C1(d4.y, s4.y) C1(d4.z, s4.z) C1(d4.w, s4.w)
            #undef C1
        }
        for (int i = start + (nvec << 2) + tid; i < end; i += 256) {   // tail
            unsigned d = (unsigned)dst[i], s = (unsigned)src[i];
            if (d < (unsigned)n && s < (unsigned)n)
                atomicAdd(&lh[d >> BIN_SHIFT], 1);
        }
        __syncthreads();
        for (int j = tid; j < nbins; j += 256) {
            int c = lh[j];
            lgb[j] = c ? atomicAdd(&gbin_cnt[slot * NBINS_MAX + j], c) : 0;
        }
        __syncthreads();
        // sweep 2: append (int4 edge loads)
        for (int i = tid; i < nvec; i += 256) {
            int4 d4 = dst4[i];
            int4 s4 = src4[i];
            #define A1(dd, ss) { unsigned d = (unsigned)(dd), s = (unsigned)(ss);   \
                if (d < (unsigned)n && s < (unsigned)n) {                           \
                    int bin = d >> BIN_SHIFT;                                       \
                    int r = atomicAdd(&lh2[bin], 1);                                \
                    int pos = lgb[bin] + r;                                         \
                    if (pos < SUBCAP)                                               \
                        binned[(size_t)bin * CAP + slot * SUBCAP + pos] =           \
                            (s << BIN_SHIFT) | (d & (BIN_SIZE - 1)); } }
            A1(d4.x, s4.x) A1(d4.y, s4.y) A1(d4.z, s4.z) A1(d4.w, s4.w)
            #undef A1
        }
        for (int i = start + (nvec << 2) + tid; i < end; i += 256) {   // tail
            unsigned d = (unsigned)dst[i], s = (unsigned)src[i];
            if (d < (unsigned)n && s < (unsigned)n) {
                int bin = d >> BIN_SHIFT;
                int r = atomicAdd(&lh2[bin], 1);
                int pos = lgb[bin] + r;
                if (pos < SUBCAP)
                    binned[(size_t)bin * CAP + slot * SUBCAP + pos] =
                        (s << BIN_SHIFT) | (d & (BIN_SIZE - 1));
            }
        }
    }
}

// ---------------- bin scan: totals over 16 slots -> exclusive scan -> bin_base; row_start[n]=total
__global__ __launch_bounds__(1024) void binscan_kernel(const int* __restrict__ gbin_cnt,
                                                       int* __restrict__ bin_base,
                                                       int* __restrict__ row_start,
                                                       int nbins, int n) {
    const int tid = threadIdx.x, lane = tid & 63, w = tid >> 6;
    int v = 0;
    if (tid < nbins) {
        #pragma unroll
        for (int s = 0; s < NSLOT; ++s) {
            int c = gbin_cnt[s * NBINS_MAX + tid];
            v += (c < SUBCAP) ? c : SUBCAP;          // clamp overflowed sub-regions
        }
    }
    int x = v;
    #pragma unroll
    for (int off = 1; off < 64; off <<= 1) {
        int y = __shfl_up(x, off);
        if (lane >= off) x += y;
    }
    __shared__ int ws[16];
    if (lane == 63) ws[w] = x;
    __syncthreads();
    int woff = 0, total = 0;
    #pragma unroll
    for (int j = 0; j < 16; ++j) {
        int s = ws[j];
        if (j < w) woff += s;
        total += s;
    }
    if (tid < nbins) bin_base[tid] = woff + (x - v);
    if (tid == 0) { bin_base[nbins] = total; row_start[n] = total; }
}

// ---------------- per-bin CSR build: block b owns nodes [b*1024, b*1024+1024)
// walks the 16 slot sub-regions of its bin; also writes dinv and dscale = dinv*xscale
__global__ __launch_bounds__(1024) void bincsr_kernel(const unsigned int* __restrict__ binned,
                                                      const int* __restrict__ bin_base,
                                                      const int* __restrict__ gbin_cnt,
                                                      const float* __restrict__ xscale,
                                                      int* __restrict__ csr_src,
                                                      int* __restrict__ row_start,
                                                      float* __restrict__ dinv,
                                                      float* __restrict__ dscale, int n) {
    __shared__ int h[BIN_SIZE];
    __shared__ int ex[BIN_SIZE];
    __shared__ int ws[16];
    __shared__ int scnt[NSLOT];
    const int b = blockIdx.x, tid = threadIdx.x, lane = tid & 63, w = tid >> 6;
    h[tid] = 0;
    if (tid < NSLOT) {
        int c = gbin_cnt[tid * NBINS_MAX + b];
        scnt[tid] = (c < SUBCAP) ? c : SUBCAP;
    }
    __syncthreads();
    const int base = bin_base[b];
    const size_t boff = (size_t)b * CAP;
    #pragma unroll
    for (int s = 0; s < NSLOT; ++s) {
        const int cs = scnt[s];
        for (int i = tid; i < cs; i += BIN_SIZE)
            atomicAdd(&h[binned[boff + s * SUBCAP + i] & (BIN_SIZE - 1)], 1);
    }
    __syncthreads();
    const int v = h[tid];
    int x = v;
    #pragma unroll
    for (int off = 1; off < 64; off <<= 1) {
        int y = __shfl_up(x, off);
        if (lane >= off) x += y;
    }
    if (lane == 63) ws[w] = x;
    __syncthreads();
    int woff = 0;
    #pragma unroll
    for (int j = 0; j < 16; ++j)
        if (j < w) woff += ws[j];
    const int excl = woff + (x - v);
    ex[tid] = excl;
    const int node = b * BIN_SIZE + tid;
    if (node < n) {
        row_start[node] = base + excl;
        float di = rsqrtf((float)(v + 1));           // +1 self loop
        dinv[node] = di;
        dscale[node] = di * xscale[node];
    }
    __syncthreads();
    h[tid] = 0;                                      // reuse as rank counters
    __syncthreads();
    #pragma unroll
    for (int s = 0; s < NSLOT; ++s) {
        const int cs = scnt[s];
        for (int i = tid; i < cs; i += BIN_SIZE) {
            unsigned p = binned[boff + s * SUBCAP + i];
            int dl = p & (BIN_SIZE - 1);
            int r = atomicAdd(&h[dl], 1);
            csr_src[base + ex[dl] + r] = (int)(p >> BIN_SHIFT);
        }
    }
}

// ---------------- MFMA GEMM: C[n,M] = A[n,K] bf16 @ W[K,M] (packed bf16) ----------------
// Epilogue: optional relu(v+bias); output bf16, or int8 + per-row scale (dscale_out = dinv*max/127)
template<int K, int M, bool BIASRELU, bool OUTINT8>
__global__ __launch_bounds__(256) void gemm_mfma_kernel(const unsigned short* __restrict__ A,
                                                        const unsigned short* __restrict__ Wp,
                                                        void* __restrict__ C_v,
                                                        const float* __restrict__ bias,
                                                        const float* __restrict__ dinv,
                                                        float* __restrict__ dscale_out, int n) {
    constexpr int NKS = K / 32;
    constexpr int NCT = M / 16;
    __shared__ unsigned short wl[K * M];            // 64 KB
    const int tid  = threadIdx.x;
    const int lane = tid & 63;
    const int wid  = tid >> 6;

    for (int i = tid; i < K * M / 8; i += 256)
        *(uint4*)&wl[(size_t)i * 8] = *(const uint4*)&Wp[(size_t)i * 8];
    __syncthreads();

    const int ntiles = (n + 63) / 64;
    for (int t = blockIdx.x; t < ntiles; t += gridDim.x) {
        const int row0 = t * 64 + wid * 16;
        int arow = row0 + (lane & 15);
        if (arow > n - 1) arow = n - 1;             // clamp (garbage rows masked at store)
        const unsigned short* ap = A + (size_t)arow * K + (lane >> 4) * 8;

        short8 afrag[NKS];
        #pragma unroll
        for (int ks = 0; ks < NKS; ++ks)
            afrag[ks] = *(const short8*)(ap + ks * 32);

        f32x4 acc[NCT] = {};
        #pragma unroll
        for (int ks = 0; ks < NKS; ++ks) {
            #pragma unroll
            for (int ct = 0; ct < NCT; ++ct) {
                short8 b = *(const short8*)&wl[((ct * NKS + ks) * 64 + lane) * 8];
                acc[ct] = __builtin_amdgcn_mfma_f32_16x16x32_bf16(afrag[ks], b, acc[ct], 0, 0, 0);
            }
        }

        // C/D layout: col = lane&15, row = (lane>>4)*4 + r   [verified m89]
        const int crow0 = row0 + (lane >> 4) * 4;
        const int ccol  = lane & 15;
        if (OUTINT8) {
            #pragma unroll
            for (int r = 0; r < 4; ++r) {
                float m = 0.f;
                #pragma unroll
                for (int ct = 0; ct < NCT; ++ct) m = fmaxf(m, fabsf(acc[ct][r]));
                #pragma unroll
                for (int off = 1; off < 16; off <<= 1) m = fmaxf(m, __shfl_xor(m, off));
                float inv = (m > 0.f) ? 127.f / m : 0.f;
                int row = crow0 + r;
                if (row < n) {
                    #pragma unroll
                    for (int ct = 0; ct < NCT; ++ct) {
                        int q = (int)rintf(acc[ct][r] * inv);
                        ((signed char*)C_v)[(size_t)row * M + ct * 16 + ccol] = (signed char)q;
                    }
                    if (ccol == 0) dscale_out[row] = dinv[row] * m * (1.f / 127.f);
                }
            }
        } else {
            #pragma unroll
            for (int ct = 0; ct < NCT; ++ct) {
                float bv = BIASRELU ? bias[ct * 16 + ccol] : 0.f;
                #pragma unroll
                for (int r = 0; r < 4; ++r) {
                    int row = crow0 + r;
                    if (row < n) {
                        float v = acc[ct][r];
                        if (BIASRELU) v = fmaxf(v + bv, 0.f);
                        ((unsigned short*)C_v)[(size_t)row * M + ct * 16 + ccol] = f2bf(v);
                    }
                }
            }
        }
    }
}

// ---------------- aggregation: out = [bias +] cw[n]*dn*H[n] + sum cw[s]*dn*H[s]
// cw = dscale (int8 H: dinv*scale) or dinv (bf16 H). dn = dinv[node].
// CH=128: 2 nodes/wave (32 lanes/node, 4 ch/lane). Edge loop unrolled x4 for MLP.
template<int CH, bool INT8IN, bool HASBIAS, bool LN>
__global__ __launch_bounds__(256) void agg_kernel(const void* __restrict__ H_v,
                                                  const int* __restrict__ row_start,
                                                  const int* __restrict__ csr_src,
                                                  const float* __restrict__ dinv,
                                                  const float* __restrict__ cw,
                                                  const float* __restrict__ bias,
                                                  const float* __restrict__ gamma,
                                                  const float* __restrict__ beta,
                                                  void* __restrict__ out_v, int n) {
    constexpr int SUBW = 32;                        // lanes per node
    static_assert(CH == SUBW * 4, "layout");
    const int lane = threadIdx.x & 63;
    const int wid  = threadIdx.x >> 6;
    int node = blockIdx.x * 8 + wid * 2 + (lane >> 5);
    if (node >= n) return;
    const int slane = lane & (SUBW - 1);
    const int c0 = slane * 4;

    const unsigned char*  H8  = (const unsigned char*)H_v;
    const unsigned short* H16 = (const unsigned short*)H_v;

    const float dn = dinv[node];
    const int e0 = row_start[node], e1 = row_start[node + 1];

    float acc[4];
    #define LOAD4(sidx, v0, v1, v2, v3)                                             \
        float v0, v1, v2, v3;                                                       \
        if (INT8IN) {                                                               \
            unsigned int p = *(const unsigned int*)&H8[(size_t)(sidx) * CH + c0];   \
            v0 = (float)(int)(signed char)(p & 0xff);                               \
            v1 = (float)(int)(signed char)((p >> 8) & 0xff);                        \
            v2 = (float)(int)(signed char)((p >> 16) & 0xff);                       \
            v3 = (float)(int)(signed char)(p >> 24);                                \
        } else {                                                                    \
            ushort4 hh = *(const ushort4*)&H16[(size_t)(sidx) * CH + c0];           \
            v0 = bf2f(hh.x); v1 = bf2f(hh.y); v2 = bf2f(hh.z); v3 = bf2f(hh.w);     \
        }
    {   // self loop: coeff = dn * cw[node]
        float c = dn * cw[node];
        LOAD4(node, h0, h1, h2, h3)
        acc[0] = h0 * c; acc[1] = h1 * c; acc[2] = h2 * c; acc[3] = h3 * c;
    }
    int e = e0;
    for (; e + 4 <= e1; e += 4) {
        int s0 = csr_src[e + 0], s1 = csr_src[e + 1];
        int s2 = csr_src[e + 2], s3 = csr_src[e + 3];
        float w0 = cw[s0] * dn, w1 = cw[s1] * dn;
        float w2 = cw[s2] * dn, w3 = cw[s3] * dn;
        LOAD4(s0, a0, a1, a2, a3)
        LOAD4(s1, b0, b1, b2, b3)
        LOAD4(s2, c0v, c1v, c2v, c3v)
        LOAD4(s3, d0, d1, d2, d3)
        acc[0] += a0 * w0;  acc[1] += a1 * w0;  acc[2] += a2 * w0;  acc[3] += a3 * w0;
        acc[0] += b0 * w1;  acc[1] += b1 * w1;  acc[2] += b2 * w1;  acc[3] += b3 * w1;
        acc[0] += c0v * w2; acc[1] += c1v * w2; acc[2] += c2v * w2; acc[3] += c3v * w2;
        acc[0] += d0 * w3;  acc[1] += d1 * w3;  acc[2] += d2 * w3;  acc[3] += d3 * w3;
    }
    for (; e < e1; ++e) {
        int s = csr_src[e];
        float c = cw[s] * dn;
        LOAD4(s, h0, h1, h2, h3)
        acc[0] += h0 * c; acc[1] += h1 * c; acc[2] += h2 * c; acc[3] += h3 * c;
    }
    #undef LOAD4

    if (HASBIAS) {
        float4 bi = *(const float4*)&bias[c0];
        acc[0] += bi.x; acc[1] += bi.y; acc[2] += bi.z; acc[3] += bi.w;
    }

    if (LN) {
        // fused LayerNorm over the sub-wave (32 lanes hold the full row)
        float s = acc[0] + acc[1] + acc[2] + acc[3];
        float ss = acc[0]*acc[0] + acc[1]*acc[1] + acc[2]*acc[2] + acc[3]*acc[3];
        #pragma unroll
        for (int off = SUBW / 2; off; off >>= 1) {
            s  += __shfl_xor(s, off);
            ss += __shfl_xor(ss, off);
        }
        float mu  = s * (1.f / (float)CH);
        float var = ss * (1.f / (float)CH) - mu * mu;
        float rstd = rsqrtf(var + 1e-5f);
        float4 g = *(const float4*)&gamma[c0];
        float4 b = *(const float4*)&beta[c0];
        f32x4 o;
        o[0] = (acc[0] - mu) * rstd * g.x + b.x;
        o[1] = (acc[1] - mu) * rstd * g.y + b.y;
        o[2] = (acc[2] - mu) * rstd * g.z + b.z;
        o[3] = (acc[3] - mu) * rstd * g.w + b.w;
        float* out = (float*)out_v;
        __builtin_nontemporal_store(o, (f32x4*)&out[(size_t)node * CH + c0]);  // final out: write-only
    } else {
        // bf16 output (re-read by next gemm as MFMA A-operand)
        ushort4 o4;
        o4.x = f2bf(acc[0]); o4.y = f2bf(acc[1]);
        o4.z = f2bf(acc[2]); o4.w = f2bf(acc[3]);
        unsigned short* out = (unsigned short*)out_v;
        *(ushort4*)&out[(size_t)node * CH + c0] = o4;
    }
}

extern "C" void kernel_launch(void* const* d_in, const int* in_sizes, int n_in,
                              void* d_out, int out_size, void* d_ws, size_t ws_size,
                              hipStream_t stream) {
    const float* x     = (const float*)d_in[0];
    const int*   ei    = (const int*)d_in[1];     // int32 (harness: integer -> const int*)
    const float* W1    = (const float*)d_in[2];
    const float* b1    = (const float*)d_in[3];
    const float* W2    = (const float*)d_in[4];
    const float* b2    = (const float*)d_in[5];
    const float* gamma = (const float*)d_in[6];
    const float* beta  = (const float*)d_in[7];
    float* out = (float*)d_out;

    const int N = in_sizes[0] / C_IN;
    const int E = in_sizes[1] / 2;
    const int* src = ei;
    const int* dst = ei + E;
    const int NBINS = (N + BIN_SIZE - 1) >> BIN_SHIFT;
    const int NBINA = (E + CHUNK_A - 1) / CHUNK_A;

    // workspace layout
    unsigned char*  xq  = (unsigned char*)d_ws;                     // N*128 B (x int8)
    unsigned short* xa  = (unsigned short*)(xq + (size_t)N * C_IN); // N*128 bf16 (S·x)
    unsigned short* g16 = xa + (size_t)N * C_IN;                    // N*256 bf16
    unsigned char*  h8  = (unsigned char*)(g16 + (size_t)N * C_HID);// N*128 B (g@W2 int8)
    unsigned short* w1p = (unsigned short*)(h8 + (size_t)N * C_OUT);// 128*256
    unsigned short* w2p = w1p + C_IN * C_HID;                       // 256*128
    float* dinv    = (float*)(w2p + C_HID * C_OUT);                 // N
    float* dscale  = dinv + N;                                      // N (dinv*xscale)
    float* xscale  = dscale + N;                                    // N
    float* dscale2 = xscale + N;                                    // N (dinv*hscale)
    int*   row_start = (int*)(dscale2 + N);                         // N+1 (pad 4)
    int*   gbin_cnt  = row_start + N + 4;                           // NSLOT*NBINS_MAX
    int*   bin_base  = gbin_cnt + NSLOT * NBINS_MAX;                // NBINS_MAX+4
    unsigned int* binned = (unsigned int*)(bin_base + NBINS_MAX + 4);  // NBINS_MAX*CAP
    int*   csr_src   = (int*)(binned + (size_t)NBINS_MAX * CAP);       // E

    hipMemsetAsync(gbin_cnt, 0, NSLOT * NBINS_MAX * sizeof(int), stream);

    // fused: quant x->int8 | pack W1 | pack W2 | bin-append edges (int4 loads, striped counters)
    prep_kernel<<<CVT_BLOCKS + 2 * PACK_BLOCKS + NBINA, 256, 0, stream>>>(
        x, xq, xscale, W1, w1p, W2, w2p, src, dst, binned, gbin_cnt, E, N);
    binscan_kernel<<<1, 1024, 0, stream>>>(gbin_cnt, bin_base, row_start, NBINS, N);
    bincsr_kernel<<<NBINS, 1024, 0, stream>>>(binned, bin_base, gbin_cnt, xscale,
                                              csr_src, row_start, dinv, dscale, N);

    // layer 1 (linearity): xa = S·x (int8 gather) ; g = relu(xa@W1 + b1)
    agg_kernel<C_IN, true, false, false><<<(N + 7) / 8, 256, 0, stream>>>(
        (const void*)xq, row_start, csr_src, dinv, dscale,
        nullptr, nullptr, nullptr, (void*)xa, N);
    gemm_mfma_kernel<C_IN, C_HID, true, false><<<512, 256, 0, stream>>>(
        xa, w1p, (void*)g16, b1, nullptr, nullptr, N);

    // layer 2: h8 = g@W2 (int8 + row scale) ; out = LN(S·h8 + b2)
    gemm_mfma_kernel<C_HID, C_OUT, false, true><<<512, 256, 0, stream>>>(
        g16, w2p, (void*)h8, nullptr, dinv, dscale2, N);
    agg_kernel<C_OUT, true, true, true><<<(N + 7) / 8, 256, 0, stream>>>(
        (const void*)h8, row_start, csr_src, dinv, dscale2, b2, gamma, beta, (void*)out, N);
}